// Round 1
// baseline (266.422 us; speedup 1.0000x reference)
//
#include <hip/hip_runtime.h>

#define NB 32
#define NC 511      // T-1 context positions
#define NK 8        // senses (center)
#define NS 8        // senses (context)
#define ND 300      // embedding dim
#define ND4 75      // float4 per row (300*4B = 1200B, 16B-aligned rows)
#define NCH 8       // c-chunks for m partials
#define CCHUNK 64
#define EPS_COS 1e-8f

// ---------------------------------------------------------------------------
// K1: one wave per (b,c). Fuses v = mean_s ctx[b,c,s,:] with
// a[b,k,c] = dot(center[b,k,:], v) / sqrt(d).  Reads ctx once (157 MB).
// ---------------------------------------------------------------------------
__global__ __launch_bounds__(256) void k_va(const float* __restrict__ ctx,
                                            const float* __restrict__ cen,
                                            float* __restrict__ v,
                                            float* __restrict__ a) {
    int b    = blockIdx.x >> 7;        // 128 blocks-per-b
    int cgrp = blockIdx.x & 127;
    int w    = threadIdx.x >> 6;       // wave in block (4 waves, 4 c's)
    int lane = threadIdx.x & 63;
    int c = cgrp * 4 + w;
    if (c >= NC) return;               // wave-uniform

    const float4* ctx4 = (const float4*)ctx + (size_t)(b * NC + c) * NS * ND4;
    int i0 = lane;
    int i1 = lane + 64;
    bool has1 = (i1 < ND4);            // lanes 0..10 own a second float4

    float4 s0 = make_float4(0.f, 0.f, 0.f, 0.f);
    float4 s1 = make_float4(0.f, 0.f, 0.f, 0.f);
#pragma unroll
    for (int s = 0; s < NS; ++s) {
        float4 x = ctx4[s * ND4 + i0];
        s0.x += x.x; s0.y += x.y; s0.z += x.z; s0.w += x.w;
        if (has1) {
            float4 y = ctx4[s * ND4 + i1];
            s1.x += y.x; s1.y += y.y; s1.z += y.z; s1.w += y.w;
        }
    }
    const float inv = 0.125f;   // 1/S
    s0.x *= inv; s0.y *= inv; s0.z *= inv; s0.w *= inv;
    s1.x *= inv; s1.y *= inv; s1.z *= inv; s1.w *= inv;

    float4* v4 = (float4*)v + (size_t)(b * NC + c) * ND4;
    v4[i0] = s0;
    if (has1) v4[i1] = s1;

    const float4* cen4 = (const float4*)cen + (size_t)b * NK * ND4;
    float pk[NK];
#pragma unroll
    for (int k = 0; k < NK; ++k) {
        float4 ca = cen4[k * ND4 + i0];
        float p = ca.x * s0.x + ca.y * s0.y + ca.z * s0.z + ca.w * s0.w;
        if (has1) {
            float4 cb = cen4[k * ND4 + i1];
            p += cb.x * s1.x + cb.y * s1.y + cb.z * s1.z + cb.w * s1.w;
        }
        pk[k] = p;
    }
#pragma unroll
    for (int off = 32; off; off >>= 1) {
#pragma unroll
        for (int k = 0; k < NK; ++k) pk[k] += __shfl_down(pk[k], off);
    }
    if (lane == 0) {
        const float scale = 0.057735026919f; // 1/sqrt(300)
#pragma unroll
        for (int k = 0; k < NK; ++k)
            a[(size_t)(b * NK + k) * NC + c] = pk[k] * scale;
    }
}

// ---------------------------------------------------------------------------
// K2: softmax over c per (b,k), in place (a -> alpha). Note the positional
// log-weight is a constant (dist>=1 -> w underflows to 0 -> log(1e-12)),
// so it cancels in the softmax and is omitted.
// ---------------------------------------------------------------------------
__global__ __launch_bounds__(256) void k_softmax(float* __restrict__ a) {
    float* p = a + (size_t)blockIdx.x * NC;
    int t = threadIdx.x;
    int lane = t & 63, w = t >> 6;
    __shared__ float rmax[4];
    __shared__ float rsum[4];

    float x0 = (t < NC) ? p[t] : -INFINITY;
    float x1 = (t + 256 < NC) ? p[t + 256] : -INFINITY;
    float mx = fmaxf(x0, x1);
#pragma unroll
    for (int off = 32; off; off >>= 1) mx = fmaxf(mx, __shfl_xor(mx, off));
    if (lane == 0) rmax[w] = mx;
    __syncthreads();
    mx = fmaxf(fmaxf(rmax[0], rmax[1]), fmaxf(rmax[2], rmax[3]));

    float e0 = (t < NC) ? __expf(x0 - mx) : 0.f;
    float e1 = (t + 256 < NC) ? __expf(x1 - mx) : 0.f;
    float s = e0 + e1;
#pragma unroll
    for (int off = 32; off; off >>= 1) s += __shfl_xor(s, off);
    if (lane == 0) rsum[w] = s;
    __syncthreads();
    float tot = rsum[0] + rsum[1] + rsum[2] + rsum[3];
    float invt = 1.f / tot;
    if (t < NC) p[t] = e0 * invt;
    if (t + 256 < NC) p[t + 256] = e1 * invt;
}

// ---------------------------------------------------------------------------
// K3: m[b,k,:] = sum_c alpha[b,k,c] * v[b,c,:], c-chunked into NCH partials
// (no atomics). Alpha chunk in LDS (broadcast reads), thread owns one dd.
// ---------------------------------------------------------------------------
__global__ __launch_bounds__(320) void k_m(const float* __restrict__ v,
                                           const float* __restrict__ alpha,
                                           float* __restrict__ part) {
    int b  = blockIdx.x >> 3;
    int ch = blockIdx.x & 7;
    int c0 = ch * CCHUNK;
    int cn = min(CCHUNK, NC - c0);
    __shared__ float al[NK][CCHUNK];
    int t = threadIdx.x;
    for (int idx = t; idx < NK * CCHUNK; idx += 320) {
        int k = idx / CCHUNK, cc = idx % CCHUNK;
        al[k][cc] = (cc < cn) ? alpha[(size_t)(b * NK + k) * NC + c0 + cc] : 0.f;
    }
    __syncthreads();
    if (t < ND) {
        float acc[NK] = {0.f, 0.f, 0.f, 0.f, 0.f, 0.f, 0.f, 0.f};
        const float* vp = v + ((size_t)b * NC + c0) * ND + t;
        for (int cc = 0; cc < cn; ++cc) {
            float vv = vp[(size_t)cc * ND];
#pragma unroll
            for (int k = 0; k < NK; ++k) acc[k] += al[k][cc] * vv;
        }
        float* pp = part + ((size_t)(ch * NB + b) * NK) * ND + t;
#pragma unroll
        for (int k = 0; k < NK; ++k) pp[(size_t)k * ND] = acc[k];
    }
}

// ---------------------------------------------------------------------------
// K4: per b — sum m partials into LDS, cosine sim per k (wave w does k=w,w+4),
// softmax q, first-max argmax, write q and pooled.
// ---------------------------------------------------------------------------
__global__ __launch_bounds__(256) void k_final(const float* __restrict__ part,
                                               const float* __restrict__ cen,
                                               float* __restrict__ out) {
    int b = blockIdx.x;
    __shared__ float m[NK * ND];
    __shared__ float sred[NK];
    __shared__ int bidx;
    int t = threadIdx.x;

    for (int idx = t; idx < NK * ND; idx += 256) {
        float s = 0.f;
#pragma unroll
        for (int ch = 0; ch < NCH; ++ch)
            s += part[(size_t)(ch * NB + b) * NK * ND + idx];
        m[idx] = s;
    }
    __syncthreads();

    int w = t >> 6, lane = t & 63;
#pragma unroll
    for (int kk = 0; kk < 2; ++kk) {
        int k = w + kk * 4;
        const float* cp = cen + (size_t)(b * NK + k) * ND;
        const float* mp = m + k * ND;
        float num = 0.f, n1 = 0.f, n2 = 0.f;
        for (int dd = lane; dd < ND; dd += 64) {
            float cv = cp[dd], mv = mp[dd];
            num += cv * mv; n1 += cv * cv; n2 += mv * mv;
        }
#pragma unroll
        for (int off = 32; off; off >>= 1) {
            num += __shfl_down(num, off);
            n1  += __shfl_down(n1, off);
            n2  += __shfl_down(n2, off);
        }
        if (lane == 0) {
            float denom = fmaxf(sqrtf(n1), EPS_COS) * fmaxf(sqrtf(n2), EPS_COS);
            sred[k] = num / denom;
        }
    }
    __syncthreads();

    if (t == 0) {
        float mx = sred[0];
#pragma unroll
        for (int k = 1; k < NK; ++k) mx = fmaxf(mx, sred[k]);
        float e[NK], sum = 0.f;
#pragma unroll
        for (int k = 0; k < NK; ++k) { e[k] = __expf(sred[k] - mx); sum += e[k]; }
        float inv = 1.f / sum;
        int best = 0; float bv = sred[0];
#pragma unroll
        for (int k = 1; k < NK; ++k) if (sred[k] > bv) { bv = sred[k]; best = k; }
#pragma unroll
        for (int k = 0; k < NK; ++k)
            out[(size_t)NB * ND + b * NK + k] = e[k] * inv;
        bidx = best;
    }
    __syncthreads();

    const float* src = cen + (size_t)(b * NK + bidx) * ND;
    for (int idx = t; idx < ND; idx += 256)
        out[(size_t)b * ND + idx] = src[idx];
}

extern "C" void kernel_launch(void* const* d_in, const int* in_sizes, int n_in,
                              void* d_out, int out_size, void* d_ws, size_t ws_size,
                              hipStream_t stream) {
    // d_in[0]=center_pos (unused: positional weight is constant after underflow)
    // d_in[1]=query_token_ids (unused)
    const float* cen = (const float*)d_in[2];   // [B,K,d]
    const float* ctx = (const float*)d_in[3];   // [B,C,S,d]
    float* out = (float*)d_out;                 // pooled [B,d] then q [B,K]

    float* v    = (float*)d_ws;                      // B*C*D   = 4,905,600 f
    float* a    = v + (size_t)NB * NC * ND;          // B*K*C   =   130,816 f
    float* part = a + (size_t)NB * NK * NC;          // NCH*B*K*D =  614,400 f
    // total ws: ~22.6 MB

    k_va<<<dim3(NB * 128), dim3(256), 0, stream>>>(ctx, cen, v, a);
    k_softmax<<<dim3(NB * NK), dim3(256), 0, stream>>>(a);
    k_m<<<dim3(NB * NCH), dim3(320), 0, stream>>>(v, a, part);
    k_final<<<dim3(NB), dim3(256), 0, stream>>>(part, cen, out);
}